// Round 1
// baseline (77.187 us; speedup 1.0000x reference)
//
#include <hip/hip_runtime.h>

// Problem constants (from reference): B=32, T=1024, C=1024, MAX_LEN=2*T=2048
#define BB 32
#define TT 1024
#define CC 1024
#define ML 2048

// Kernel 1: per-batch masked inclusive scan of durations.
// One block per batch, TT threads. Hillis-Steele double-buffer scan in LDS.
__global__ __launch_bounds__(TT) void lr_scan_kernel(const int* __restrict__ dur,
                                                     const int* __restrict__ seqlen,
                                                     int* __restrict__ cum) {
    __shared__ int buf[2][TT];
    const int b = blockIdx.x;
    const int t = threadIdx.x;
    const int sl = seqlen[b];
    int d = (t < sl) ? dur[b * TT + t] : 0;
    buf[0][t] = d;
    __syncthreads();
    int src = 0;
    for (int off = 1; off < TT; off <<= 1) {
        int v = buf[src][t];
        if (t >= off) v += buf[src][t - off];
        buf[src ^ 1][t] = v;
        __syncthreads();
        src ^= 1;
    }
    cum[b * TT + t] = buf[src][t];
}

// Kernel 2: one block per output row (b, pos). Thread 0 does the
// searchsorted(cum[b], pos, side='right') binary search (cum is L2-resident,
// 4 KiB/batch); the block then copies x[b, t, :] -> out[b, pos, :] as
// 256 x float4 (4 KiB), or writes zeros for pos >= total.
__global__ __launch_bounds__(256) void lr_gather_kernel(const float* __restrict__ x,
                                                        const int* __restrict__ cum,
                                                        float* __restrict__ out) {
    const int b   = blockIdx.x / ML;
    const int pos = blockIdx.x % ML;
    const int* __restrict__ c = cum + b * TT;

    __shared__ int s_t;
    if (threadIdx.x == 0) {
        const int total = c[TT - 1];
        if (pos >= total) {
            s_t = -1;
        } else {
            // first index with c[idx] > pos  (searchsorted side='right')
            int lo = 0, hi = TT;
            while (lo < hi) {
                const int mid = (lo + hi) >> 1;
                if (c[mid] <= pos) lo = mid + 1; else hi = mid;
            }
            s_t = lo;  // guaranteed < TT because c[TT-1] = total > pos
        }
    }
    __syncthreads();
    const int t = s_t;

    float4* __restrict__ orow = (float4*)(out + ((size_t)b * ML + pos) * CC);
    if (t < 0) {
        orow[threadIdx.x] = make_float4(0.f, 0.f, 0.f, 0.f);
    } else {
        const float4* __restrict__ xrow = (const float4*)(x + ((size_t)b * TT + t) * CC);
        orow[threadIdx.x] = xrow[threadIdx.x];
    }
}

extern "C" void kernel_launch(void* const* d_in, const int* in_sizes, int n_in,
                              void* d_out, int out_size, void* d_ws, size_t ws_size,
                              hipStream_t stream) {
    const float* x   = (const float*)d_in[0];
    const int*   dur = (const int*)d_in[1];
    const int*   sl  = (const int*)d_in[2];
    // d_in[3] is max_len (== 2048), hardcoded as ML.
    float* out = (float*)d_out;
    int*   cum = (int*)d_ws;  // BB*TT ints = 128 KiB of workspace

    lr_scan_kernel<<<BB, TT, 0, stream>>>(dur, sl, cum);
    lr_gather_kernel<<<BB * ML, 256, 0, stream>>>(x, cum, out);
}

// Round 2
// 63.692 us; speedup vs baseline: 1.2119x; 1.2119x over previous
//
#include <hip/hip_runtime.h>

// Problem constants (from reference): B=32, T=1024, C=1024, MAX_LEN=2*T=2048
#define BB 32
#define TT 1024
#define CC 1024
#define ML 2048

// Kernel 1: per-batch masked inclusive scan of durations + SCATTER of the
// position->token index map. One block per batch, TT threads.
// After the Hillis-Steele scan, token t owns output positions
// [cum[t-1], cum[t]) (at most 2, since durations <= 2) and writes its own
// index there; the tail [total, ML) is filled with -1.
__global__ __launch_bounds__(TT) void lr_scan_scatter(const int* __restrict__ dur,
                                                      const int* __restrict__ seqlen,
                                                      int* __restrict__ tidx) {
    __shared__ int buf[2][TT];
    const int b = blockIdx.x;
    const int t = threadIdx.x;
    const int sl = seqlen[b];
    const int d = (t < sl) ? dur[b * TT + t] : 0;
    buf[0][t] = d;
    __syncthreads();
    int src = 0;
    for (int off = 1; off < TT; off <<= 1) {
        int v = buf[src][t];
        if (t >= off) v += buf[src][t - off];
        buf[src ^ 1][t] = v;
        __syncthreads();
        src ^= 1;
    }
    const int end   = buf[src][t];       // inclusive-scan value = cum[t]
    const int start = end - d;           // cum[t-1]
    int* __restrict__ row = tidx + b * ML;
    for (int p = start; p < end; ++p)    // <= 2 iterations
        row[p] = t;
    const int total = buf[src][TT - 1];  // broadcast read, post-barrier
    for (int p = total + t; p < ML; p += TT)
        row[p] = -1;
}

// Kernel 2: pure copy. One block per output row (b, pos); t_idx load is
// block-uniform (scalar-load), no LDS, no barrier. 256 threads x float4
// = 4 KiB per row; -1 rows write zeros.
__global__ __launch_bounds__(256) void lr_gather(const float* __restrict__ x,
                                                 const int* __restrict__ tidx,
                                                 float4* __restrict__ out) {
    const int row = blockIdx.x;          // 0 .. BB*ML-1
    const int b   = row >> 11;           // row / ML
    const int t   = tidx[row];
    float4 v = make_float4(0.f, 0.f, 0.f, 0.f);
    if (t >= 0) {
        const float4* __restrict__ xrow =
            (const float4*)(x + ((size_t)b * TT + t) * CC);
        v = xrow[threadIdx.x];
    }
    out[(size_t)row * (CC / 4) + threadIdx.x] = v;
}

extern "C" void kernel_launch(void* const* d_in, const int* in_sizes, int n_in,
                              void* d_out, int out_size, void* d_ws, size_t ws_size,
                              hipStream_t stream) {
    const float* x   = (const float*)d_in[0];
    const int*   dur = (const int*)d_in[1];
    const int*   sl  = (const int*)d_in[2];
    // d_in[3] is max_len (== 2048), hardcoded as ML.
    float* out  = (float*)d_out;
    int*   tidx = (int*)d_ws;  // BB*ML ints = 256 KiB of workspace

    lr_scan_scatter<<<BB, TT, 0, stream>>>(dur, sl, tidx);
    lr_gather<<<BB * ML, 256, 0, stream>>>(x, tidx, (float4*)out);
}

// Round 6
// 54.226 us; speedup vs baseline: 1.4234x; 1.1746x over previous
//
#include <hip/hip_runtime.h>

// Problem constants (from reference): B=32, T=1024, C=1024, MAX_LEN=2*T=2048
#define BB 32
#define TT 1024
#define CC 1024
#define ML 2048

// Native clang vector (HIP's float4 is a class; nontemporal builtin rejects it)
typedef float vfloat4 __attribute__((ext_vector_type(4)));

// Kernel 1: per-batch masked inclusive scan of durations + scatter of the
// position->token map. One block per batch, 256 threads x 4 tokens each.
// Wave-level shfl scan (no LDS rounds) + 4-wave combine: 2 barriers total.
__global__ __launch_bounds__(256) void lr_scan_scatter(const int* __restrict__ dur,
                                                       const int* __restrict__ seqlen,
                                                       int* __restrict__ tidx) {
    const int b    = blockIdx.x;
    const int tid  = threadIdx.x;           // 0..255
    const int lane = tid & 63;
    const int wave = tid >> 6;               // 0..3
    const int sl   = seqlen[b];
    const int base = tid * 4;                // first of this thread's 4 tokens

    const int4 dv = ((const int4*)(dur + b * TT))[tid];
    const int d0 = (base + 0 < sl) ? dv.x : 0;
    const int d1 = (base + 1 < sl) ? dv.y : 0;
    const int d2 = (base + 2 < sl) ? dv.z : 0;
    const int d3 = (base + 3 < sl) ? dv.w : 0;
    const int local = d0 + d1 + d2 + d3;

    // Inclusive scan of `local` across the 64-lane wave.
    int v = local;
    #pragma unroll
    for (int off = 1; off < 64; off <<= 1) {
        const int n = __shfl_up(v, off, 64);
        if (lane >= off) v += n;
    }

    __shared__ int wsum[4];
    __shared__ int s_total;
    if (lane == 63) wsum[wave] = v;
    __syncthreads();
    int woff = 0;
    #pragma unroll
    for (int w = 0; w < 3; ++w)
        if (w < wave) woff += wsum[w];

    const int excl = woff + v - local;       // exclusive prefix of this thread
    const int c0 = excl + d0;
    const int c1 = c0 + d1;
    const int c2 = c1 + d2;
    const int c3 = c2 + d3;

    int* __restrict__ row = tidx + b * ML;
    for (int p = excl; p < c0; ++p) row[p] = base + 0;   // <=2 iters each
    for (int p = c0;   p < c1; ++p) row[p] = base + 1;
    for (int p = c1;   p < c2; ++p) row[p] = base + 2;
    for (int p = c2;   p < c3; ++p) row[p] = base + 3;

    if (tid == 255) s_total = c3;            // thread 255's inclusive = total
    __syncthreads();
    const int total = s_total;
    for (int p = total + tid; p < ML; p += 256) row[p] = -1;
}

// Kernel 2: pure copy, 4 consecutive output rows per 256-thread block.
// t_idx for the 4 rows loads as one (scalar) int4; duplicate source rows
// (duration=2 -> adjacent positions, same t) hit L1 within the block.
// Output is write-once never-read -> nontemporal stores keep L2 for x.
__global__ __launch_bounds__(256) void lr_gather(const float* __restrict__ x,
                                                 const int* __restrict__ tidx,
                                                 vfloat4* __restrict__ out) {
    const int r0 = blockIdx.x * 4;           // first output row of this block
    const int b  = r0 >> 11;                 // row / ML; ML%4==0 so same batch
    const int4 tv = ((const int4*)tidx)[blockIdx.x];
    const int ts[4] = {tv.x, tv.y, tv.z, tv.w};

    const vfloat4* __restrict__ xb = (const vfloat4*)(x + (size_t)b * TT * CC);
    vfloat4* __restrict__ o = out + (size_t)r0 * (CC / 4) + threadIdx.x;

    #pragma unroll
    for (int i = 0; i < 4; ++i) {
        const int t = ts[i];
        vfloat4 v = (vfloat4)(0.f);
        if (t >= 0) v = xb[(size_t)t * (CC / 4) + threadIdx.x];
        __builtin_nontemporal_store(v, o + i * (CC / 4));
    }
}

extern "C" void kernel_launch(void* const* d_in, const int* in_sizes, int n_in,
                              void* d_out, int out_size, void* d_ws, size_t ws_size,
                              hipStream_t stream) {
    const float* x   = (const float*)d_in[0];
    const int*   dur = (const int*)d_in[1];
    const int*   sl  = (const int*)d_in[2];
    // d_in[3] is max_len (== 2048), hardcoded as ML.
    float* out  = (float*)d_out;
    int*   tidx = (int*)d_ws;  // BB*ML ints = 256 KiB of workspace

    lr_scan_scatter<<<BB, 256, 0, stream>>>(dur, sl, tidx);
    lr_gather<<<(BB * ML) / 4, 256, 0, stream>>>(x, tidx, (vfloat4*)out);
}